// Round 7
// baseline (369.598 us; speedup 1.0000x reference)
//
#include <hip/hip_runtime.h>
#include <math.h>
#include <stdint.h>

constexpr int kB = 4;
constexpr int kS = 2048;
constexpr int kD = 1024;
constexpr int kH = 16;
constexpr int kHD = 64;

typedef __bf16 bf16;
typedef __attribute__((ext_vector_type(4))) __bf16 bf16x4;
typedef __attribute__((ext_vector_type(8))) __bf16 bf16x8;
typedef __attribute__((ext_vector_type(4))) float f32x4;
typedef __attribute__((ext_vector_type(4))) short short4v;

__device__ __forceinline__ f32x4 mfma16x16x32(bf16x8 a, bf16x8 b, f32x4 c) {
    return __builtin_amdgcn_mfma_f32_16x16x32_bf16(a, b, c, 0, 0, 0);
}

// K=16 MFMA: A[m=lane&15][k=quad*4+i], B[k=quad*4+i][n=lane&15], C/D standard.
__device__ __forceinline__ f32x4 mfma16x16x16(bf16x4 a, bf16x4 b, f32x4 c) {
#if __has_builtin(__builtin_amdgcn_mfma_f32_16x16x16bf16_1k)
    return __builtin_amdgcn_mfma_f32_16x16x16bf16_1k(
        __builtin_bit_cast(short4v, a), __builtin_bit_cast(short4v, b), c, 0, 0, 0);
#else
    // zero-pad to K=32: regs 0..3 map to k=quad*8+{0..3} consistently for A and B
    bf16x8 az = {}, bz = {};
    az[0] = a[0]; az[1] = a[1]; az[2] = a[2]; az[3] = a[3];
    bz[0] = b[0]; bz[1] = b[1]; bz[2] = b[2]; bz[3] = b[3];
    return __builtin_amdgcn_mfma_f32_16x16x32_bf16(az, bz, c, 0, 0, 0);
#endif
}

#if __has_builtin(__builtin_amdgcn_exp2f)
#define EXP2F(x) __builtin_amdgcn_exp2f(x)
#else
#define EXP2F(x) exp2f(x)
#endif

// async 16B global->LDS. lds base must be wave-uniform; HW adds lane*16.
__device__ __forceinline__ void load_lds16(const bf16* g, bf16* lds) {
    __builtin_amdgcn_global_load_lds(
        (const __attribute__((address_space(1))) void*)g,
        (__attribute__((address_space(3))) void*)lds, 16, 0, 0);
}

// ---------------------------------------------------------------------------
// prep_x: fp32 -> bf16 convert of x (8192x1024).
// ---------------------------------------------------------------------------
__global__ __launch_bounds__(256) void prep_x(const float* __restrict__ x,
                                              bf16* __restrict__ xb) {
    size_t i = ((size_t)blockIdx.x * 256 + threadIdx.x) * 8;
    float4 f0 = *(const float4*)(x + i);
    float4 f1 = *(const float4*)(x + i + 4);
    bf16x8 v;
    v[0] = (bf16)f0.x; v[1] = (bf16)f0.y; v[2] = (bf16)f0.z; v[3] = (bf16)f0.w;
    v[4] = (bf16)f1.x; v[5] = (bf16)f1.y; v[6] = (bf16)f1.z; v[7] = (bf16)f1.w;
    *(bf16x8*)(xb + i) = v;
}

// ---------------------------------------------------------------------------
// prep_w: Wt[z*1024 + n][k] = W_z[k][n] * scale_z (bf16, transposed)
// z=0 Wq scaled by 0.125*log2(e) (exp2-domain softmax), 1=Wk, 2=Wv, 3=Wo.
// ---------------------------------------------------------------------------
__global__ __launch_bounds__(256) void prep_w(const float* __restrict__ Wq,
                                              const float* __restrict__ Wk,
                                              const float* __restrict__ Wv,
                                              const float* __restrict__ Wo,
                                              bf16* __restrict__ Wt) {
    __shared__ bf16 t[64 * 72];
    const int z = blockIdx.z;
    const float* W = (z == 0) ? Wq : (z == 1) ? Wk : (z == 2) ? Wv : Wo;
    const float scale = (z == 0) ? 0.18033688011112042f : 1.0f;
    const int k0 = blockIdx.x * 64, n0 = blockIdx.y * 64;
    const int tid = threadIdx.x;
    for (int p = 0; p < 16; ++p) {
        int idx = tid + p * 256;
        int r = idx >> 6, c = idx & 63;
        t[r * 72 + c] = (bf16)(W[(size_t)(k0 + r) * kD + n0 + c] * scale);
    }
    __syncthreads();
    for (int p = 0; p < 16; ++p) {
        int idx = tid + p * 256;
        int r = idx >> 6, c = idx & 63;
        Wt[(size_t)(z * 1024 + n0 + r) * kD + k0 + c] = t[c * 72 + r];
    }
}

// ---------------------------------------------------------------------------
// qkv_gemm: m97 structure. 128x128 tile, BK=64, unpadded LDS, staged via
// global_load_lds width=16.  4 waves 2x2, each 64x64.
// Q,K -> [B,H,S,HD]; V -> transposed [B,H,HD,S].
// ---------------------------------------------------------------------------
__global__ __launch_bounds__(256) void qkv_gemm(
    const bf16* __restrict__ xb, const bf16* __restrict__ Wt,
    bf16* __restrict__ qo, bf16* __restrict__ ko, bf16* __restrict__ vto)
{
    __shared__ bf16 As[128 * 64];
    __shared__ bf16 Bs[128 * 64];

    const int tid  = threadIdx.x;
    const int wave = tid >> 6;
    const int lane = tid & 63;
    const int quad = lane >> 4;
    const int lr   = lane & 15;
    const int wm   = wave >> 1, wn = wave & 1;

    const int m0 = blockIdx.x * 128;
    const int n0 = blockIdx.y * 128;

    const int sr = tid >> 3, sc = tid & 7;

    f32x4 acc[4][4];
#pragma unroll
    for (int i = 0; i < 4; ++i)
#pragma unroll
        for (int nt = 0; nt < 4; ++nt) acc[i][nt] = f32x4{0.f, 0.f, 0.f, 0.f};

    for (int k0 = 0; k0 < kD; k0 += 64) {
        __syncthreads();
#pragma unroll
        for (int p = 0; p < 4; ++p) {
            int r = p * 32 + sr;
            load_lds16(&xb[(size_t)(m0 + r) * kD + k0 + sc * 8],
                       &As[(p * 256 + wave * 64) * 8]);
            load_lds16(&Wt[(size_t)(n0 + r) * kD + k0 + sc * 8],
                       &Bs[(p * 256 + wave * 64) * 8]);
        }
        __syncthreads();
#pragma unroll
        for (int kk = 0; kk < 2; ++kk) {
            bf16x8 a[4], b[4];
#pragma unroll
            for (int i = 0; i < 4; ++i)
                a[i] = *(const bf16x8*)&As[(wm * 64 + i * 16 + lr) * 64 + kk * 32 + quad * 8];
#pragma unroll
            for (int nt = 0; nt < 4; ++nt)
                b[nt] = *(const bf16x8*)&Bs[(wn * 64 + nt * 16 + lr) * 64 + kk * 32 + quad * 8];
#pragma unroll
            for (int i = 0; i < 4; ++i)
#pragma unroll
                for (int nt = 0; nt < 4; ++nt)
                    acc[i][nt] = mfma16x16x32(a[i], b[nt], acc[i][nt]);
        }
    }

    const int w_idx = n0 >> 10;               // 0=Q,1=K,2=V (uniform per block)
    if (w_idx < 2) {
        bf16* dst = (w_idx == 0) ? qo : ko;   // [B,H,S,HD]
#pragma unroll
        for (int i = 0; i < 4; ++i)
#pragma unroll
            for (int nt = 0; nt < 4; ++nt) {
                int n   = n0 + wn * 64 + nt * 16 + lr;
                int col = n & 1023, h = col >> 6, hd = col & 63;
#pragma unroll
                for (int j = 0; j < 4; ++j) {
                    int m = m0 + wm * 64 + i * 16 + quad * 4 + j;
                    int b = m >> 11, s = m & 2047;
                    dst[((size_t)(b * kH + h) * kS + s) * kHD + hd] = (bf16)acc[i][nt][j];
                }
            }
    } else {
        // V transposed: [B,H,HD,S]; j walks s -> bf16x4 stores
#pragma unroll
        for (int i = 0; i < 4; ++i)
#pragma unroll
            for (int nt = 0; nt < 4; ++nt) {
                int n   = n0 + wn * 64 + nt * 16 + lr;
                int col = n & 1023, h = col >> 6, hd = col & 63;
                int mb  = m0 + wm * 64 + i * 16 + quad * 4;
                int b = mb >> 11, s = mb & 2047;
                bf16x4 pk;
#pragma unroll
                for (int j = 0; j < 4; ++j) pk[j] = (bf16)acc[i][nt][j];
                *(bf16x4*)&vto[((size_t)(b * kH + h) * kHD + hd) * kS + s] = pk;
            }
    }
}

// ---------------------------------------------------------------------------
// attn v7: all-register causal attention (no LDS in the k-loop).
// Operand-swap trick: S^T = K·Q^T via 16x16x32 (A=K-frag, B=Q-frag-as-B);
// S^T's C-layout (lane(quad,lr) holds S[q=lr][key=quad*4+j]) IS the A-frag
// layout of the K=16 MFMA, so P goes exp2->pack->PV entirely in registers.
// V B-frags (K=16) are 4 contiguous keys of V^T -> 8B vector loads.
// One wave owns 64 q-rows; l accumulates per-lane (2 shuffles at epilogue).
// Grid (64 bh, 16 qt) x 128 threads = 2048 waves, all resident, lock-step.
// ---------------------------------------------------------------------------
__device__ __forceinline__ void attn_tile_v7(
    const bf16* __restrict__ kb_p, const bf16* __restrict__ vt_p, size_t koff,
    bf16x8 (&aq)[4][2], bf16x8 (&kf)[4][2], bf16x8 (&kfN)[4][2],
    f32x4 (&o)[4][4], float (&lsum)[4],
    int kt, int nkt, int base, int quad, int lr)
{
    const int k0 = kt * 64;
    // V B-frags for this tile: vb[nt][ht] = V^T[hd=ht*16+lr][k0+nt*16+quad*4 ..+3]
    bf16x4 vb[4][4];
#pragma unroll
    for (int ht = 0; ht < 4; ++ht)
#pragma unroll
        for (int nt = 0; nt < 4; ++nt)
            vb[nt][ht] = *(const bf16x4*)
                &vt_p[(size_t)(ht * 16 + lr) * kS + k0 + nt * 16 + quad * 4];
    // prefetch next K tile into the alternate register buffer
    if (kt + 1 < nkt) {
        const bf16* kr0 = kb_p + koff + (size_t)(kt + 1) * 64 * kHD;
#pragma unroll
        for (int nt = 0; nt < 4; ++nt) {
            kfN[nt][0] = *(const bf16x8*)(kr0 + nt * 1024);
            kfN[nt][1] = *(const bf16x8*)(kr0 + nt * 1024 + 32);
        }
    }
    const bool lastt = (kt == nkt - 1);
#pragma unroll
    for (int g = 0; g < 4; ++g) {
        // S^T tile: D[key_local=quad*4+j][q=lr] summed over d (2 halves)
        f32x4 sg[4];
#pragma unroll
        for (int nt = 0; nt < 4; ++nt) {
            sg[nt] = mfma16x16x32(kf[nt][0], aq[g][0], f32x4{0.f, 0.f, 0.f, 0.f});
            sg[nt] = mfma16x16x32(kf[nt][1], aq[g][1], sg[nt]);
        }
        const int qg = base + g * 16 + lr;
#pragma unroll
        for (int nt = 0; nt < 4; ++nt) {
            bf16x4 pv;
#pragma unroll
            for (int j = 0; j < 4; ++j) {
                float s = sg[nt][j];
                if (lastt)
                    s = (k0 + nt * 16 + quad * 4 + j > qg) ? -3.0e38f : s;
                float p = EXP2F(s);
                pv[j] = (bf16)p;
                lsum[g] += (float)pv[j];   // l consistent with bf16 P
            }
#pragma unroll
            for (int ht = 0; ht < 4; ++ht)
                o[g][ht] = mfma16x16x16(pv, vb[nt][ht], o[g][ht]);
        }
    }
}

__global__ __launch_bounds__(128, 2) void attn(
    const bf16* __restrict__ q, const bf16* __restrict__ k,
    const bf16* __restrict__ vt, bf16* __restrict__ ctx)
{
    const int tid  = threadIdx.x;
    const int wave = tid >> 6;
    const int lane = tid & 63;
    const int quad = lane >> 4;
    const int lr   = lane & 15;

    const int bh = blockIdx.x;
    // qt LUT: heavy-first AND per-CU-column balanced (groups of 4 spaced by 4
    // sum to 30 each under round-robin block->CU assignment)
    const int lut[16] = {15, 14, 13, 12, 8, 9, 10, 11, 7, 6, 5, 4, 0, 1, 2, 3};
    const int qt = lut[blockIdx.y];

    const bf16* qb_p = q  + (size_t)bh * kS * kHD;
    const bf16* kb_p = k  + (size_t)bh * kS * kHD;
    const bf16* vt_p = vt + (size_t)bh * kHD * kS;   // [hd][s]

    const int base = qt * 128 + wave * 64;           // this wave's first q-row
    const int nkt  = (base >> 6) + 1;

    // Q fragments (used as B-operand of the S^T MFMA): 4 groups x 2 d-halves
    bf16x8 aq[4][2];
#pragma unroll
    for (int g = 0; g < 4; ++g)
#pragma unroll
        for (int kk = 0; kk < 2; ++kk)
            aq[g][kk] = *(const bf16x8*)
                &qb_p[(size_t)(base + g * 16 + lr) * kHD + kk * 32 + quad * 8];

    f32x4 o[4][4];
    float lsum[4] = {0.f, 0.f, 0.f, 0.f};
#pragma unroll
    for (int g = 0; g < 4; ++g)
#pragma unroll
        for (int ht = 0; ht < 4; ++ht) o[g][ht] = f32x4{0.f, 0.f, 0.f, 0.f};

    const size_t koff = (size_t)lr * kHD + quad * 8;

    bf16x8 kfA[4][2], kfB[4][2];
    {
        const bf16* kr0 = kb_p + koff;
#pragma unroll
        for (int nt = 0; nt < 4; ++nt) {
            kfA[nt][0] = *(const bf16x8*)(kr0 + nt * 1024);
            kfA[nt][1] = *(const bf16x8*)(kr0 + nt * 1024 + 32);
        }
    }

    int kt = 0;
    for (;;) {
        attn_tile_v7(kb_p, vt_p, koff, aq, kfA, kfB, o, lsum,
                     kt, nkt, base, quad, lr);
        ++kt; if (kt == nkt) break;
        attn_tile_v7(kb_p, vt_p, koff, aq, kfB, kfA, o, lsum,
                     kt, nkt, base, quad, lr);
        ++kt; if (kt == nkt) break;
    }

    // l: sum partials across quads (same lr = same q), then fetch per-row
#pragma unroll
    for (int g = 0; g < 4; ++g) {
        lsum[g] += __shfl_xor(lsum[g], 16);
        lsum[g] += __shfl_xor(lsum[g], 32);
    }

    const int b = bh >> 4;
    const int h = bh & 15;
#pragma unroll
    for (int g = 0; g < 4; ++g) {
        float inv[4];
#pragma unroll
        for (int j = 0; j < 4; ++j)
            inv[j] = 1.0f / __shfl(lsum[g], quad * 4 + j, 16);
#pragma unroll
        for (int ht = 0; ht < 4; ++ht) {
#pragma unroll
            for (int j = 0; j < 4; ++j) {
                int qg = base + g * 16 + quad * 4 + j;
                ctx[((size_t)(b * kS + qg)) * kD + h * kHD + ht * 16 + lr] =
                    (bf16)(o[g][ht][j] * inv[j]);
            }
        }
    }
}

// ---------------------------------------------------------------------------
// out_gemm: out = ctx @ Wo + bo (fp32).  Same m97 structure.
// ---------------------------------------------------------------------------
__global__ __launch_bounds__(256) void out_gemm(
    const bf16* __restrict__ ctxb, const bf16* __restrict__ Wto,
    const float* __restrict__ bo, float* __restrict__ out)
{
    __shared__ bf16 As[128 * 64];
    __shared__ bf16 Bs[128 * 64];

    const int tid  = threadIdx.x;
    const int wave = tid >> 6;
    const int lane = tid & 63;
    const int quad = lane >> 4;
    const int lr   = lane & 15;
    const int wm   = wave >> 1, wn = wave & 1;

    const int m0 = blockIdx.x * 128;
    const int n0 = blockIdx.y * 128;

    const int sr = tid >> 3, sc = tid & 7;

    f32x4 acc[4][4];
#pragma unroll
    for (int i = 0; i < 4; ++i)
#pragma unroll
        for (int nt = 0; nt < 4; ++nt) acc[i][nt] = f32x4{0.f, 0.f, 0.f, 0.f};

    for (int k0 = 0; k0 < kD; k0 += 64) {
        __syncthreads();
#pragma unroll
        for (int p = 0; p < 4; ++p) {
            int r = p * 32 + sr;
            load_lds16(&ctxb[(size_t)(m0 + r) * kD + k0 + sc * 8],
                       &As[(p * 256 + wave * 64) * 8]);
            load_lds16(&Wto[(size_t)(n0 + r) * kD + k0 + sc * 8],
                       &Bs[(p * 256 + wave * 64) * 8]);
        }
        __syncthreads();
#pragma unroll
        for (int kk = 0; kk < 2; ++kk) {
            bf16x8 a[4], b[4];
#pragma unroll
            for (int i = 0; i < 4; ++i)
                a[i] = *(const bf16x8*)&As[(wm * 64 + i * 16 + lr) * 64 + kk * 32 + quad * 8];
#pragma unroll
            for (int nt = 0; nt < 4; ++nt)
                b[nt] = *(const bf16x8*)&Bs[(wn * 64 + nt * 16 + lr) * 64 + kk * 32 + quad * 8];
#pragma unroll
            for (int i = 0; i < 4; ++i)
#pragma unroll
                for (int nt = 0; nt < 4; ++nt)
                    acc[i][nt] = mfma16x16x32(a[i], b[nt], acc[i][nt]);
        }
    }

#pragma unroll
    for (int nt = 0; nt < 4; ++nt) {
        int n = n0 + wn * 64 + nt * 16 + lr;
        float bias = bo[n];
#pragma unroll
        for (int i = 0; i < 4; ++i)
#pragma unroll
            for (int j = 0; j < 4; ++j) {
                int m = m0 + wm * 64 + i * 16 + quad * 4 + j;
                out[(size_t)m * kD + n] = acc[i][nt][j] + bias;
            }
    }
}

// ---------------------------------------------------------------------------
extern "C" void kernel_launch(void* const* d_in, const int* in_sizes, int n_in,
                              void* d_out, int out_size, void* d_ws, size_t ws_size,
                              hipStream_t stream) {
    const float* x  = (const float*)d_in[0];
    const float* Wq = (const float*)d_in[1];
    const float* Wk = (const float*)d_in[2];
    const float* Wv = (const float*)d_in[3];
    const float* Wo = (const float*)d_in[4];
    const float* bo = (const float*)d_in[5];
    float* out = (float*)d_out;

    const size_t n_x   = (size_t)kB * kS * kD;       // 8,388,608
    const size_t n_w   = (size_t)4 * kD * kD;        // 4,194,304
    const size_t n_mat = (size_t)kB * kH * kS * kHD; // 8,388,608

    bf16* xb  = (bf16*)d_ws;        // 16 MB (reused as ctx after qkv_gemm)
    bf16* Wt  = xb + n_x;           // 8 MB
    bf16* Qm  = Wt + n_w;           // 16 MB [B,H,S,HD]
    bf16* Km  = Qm + n_mat;         // 16 MB [B,H,S,HD]
    bf16* Vt  = Km + n_mat;         // 16 MB [B,H,HD,S]
    bf16* ctx = xb;                 // reuse: x dead after qkv_gemm

    prep_x<<<dim3((int)(n_x / (256 * 8))), dim3(256), 0, stream>>>(x, xb);
    prep_w<<<dim3(16, 16, 4), dim3(256), 0, stream>>>(Wq, Wk, Wv, Wo, Wt);
    qkv_gemm<<<dim3(8192 / 128, 3072 / 128), dim3(256), 0, stream>>>(xb, Wt, Qm, Km, Vt);
    attn<<<dim3(kB * kH, 16), dim3(128), 0, stream>>>(Qm, Km, Vt, ctx);
    out_gemm<<<dim3(8192 / 128, 1024 / 128), dim3(256), 0, stream>>>(
        ctx, Wt + (size_t)3 * kD * kD, bo, out);
}